// Round 2
// baseline (34037.302 us; speedup 1.0000x reference)
//
#include <hip/hip_runtime.h>

#define BB 256
#define TT 2048
#define HH 128
#define G4 512     // 4*H gate rows
#define INW 4
#define OUTW 4
#define TC 56      // time-chunk; LDS-resident
#define NT 512

__device__ __forceinline__ float sigm(float x) {
    // 1/(1+e^-x); safe at +-inf (exp->inf -> 0, exp->0 -> 1)
    return __fdividef(1.f, 1.f + __expf(-x));
}
__device__ __forceinline__ float tanh_(float x) {
    // 2*sigmoid(2x)-1; overflow-safe on both sides
    return __fdividef(2.f, 1.f + __expf(-2.f * x)) - 1.f;
}

// waves_per_eu(2,2): the 144KB dynamic LDS pins us to 1 block/CU = 8 waves = 2/EU
// anyway; telling the compiler so raises the VGPR budget to 256 and keeps the
// 128-float weight row in registers instead of scratch (R1: VGPR=128 + 35GB of
// scratch FETCH).
extern "C" __global__ void
__attribute__((amdgpu_flat_work_group_size(NT, NT)))
__attribute__((amdgpu_waves_per_eu(2, 2)))
lstm2_fused(const float* __restrict__ x,
            const float* __restrict__ Wih0, const float* __restrict__ Whh0,
            const float* __restrict__ bih0, const float* __restrict__ bhh0,
            const float* __restrict__ Wih1, const float* __restrict__ Whh1,
            const float* __restrict__ bih1, const float* __restrict__ bhh1,
            const float* __restrict__ Wlin, const float* __restrict__ blin,
            float* __restrict__ out)
{
    extern __shared__ float lds[];
    float* h1c  = lds;                    // (TC+1)*HH : row i = h1 at local step i-1 (row0 = carry)
    float* xg1c = h1c + (TC + 1) * HH;    // TC*G4    : layer-1 input gates for the chunk
    float* gbuf = xg1c + TC * G4;         // G4       : activated gates exchange
    float* h2b  = gbuf + G4;              // HH       : current layer-1 hidden
    float* xc   = h2b + HH;               // TC*INW   : x chunk

    const int r = threadIdx.x;            // gate row 0..511
    const int b = blockIdx.x;             // batch element

    const float bias0 = bih0[r] + bhh0[r];
    const float bias1 = bih1[r] + bhh1[r];
    const float wx0 = Wih0[r*INW+0], wx1 = Wih0[r*INW+1],
                wx2 = Wih0[r*INW+2], wx3 = Wih0[r*INW+3];

    // projection params (waves 0..3 handle outputs 0..3)
    float wl0 = 0.f, wl1 = 0.f, bl = 0.f;
    if (r < OUTW * 64) {
        const int o = r >> 6, l = r & 63;
        wl0 = Wlin[o*HH + l];
        wl1 = Wlin[o*HH + 64 + l];
        bl  = blin[o];
    }

    float c1 = 0.f, c2 = 0.f;             // cell states (threads r<HH own unit r)
    if (r < HH) { h1c[r] = 0.f; h2b[r] = 0.f; }

    float w[HH];                          // register-resident weight row (static indexing only)

    const float* xb   = x   + (size_t)b * TT * INW;
    float*       vout = out + (size_t)b * TT * OUTW;
    float*       zout = out + (size_t)BB * TT * OUTW + (size_t)b * HH;

    for (int t0 = 0; t0 < TT; t0 += TC) {
        const int tc = (TT - t0 < TC) ? (TT - t0) : TC;

        // carry h1 from previous (always-full) chunk into row 0
        if (t0 > 0 && r < HH) h1c[r] = h1c[TC * HH + r];
        // stage x chunk
        for (int i = r; i < tc * INW; i += NT) xc[i] = xb[t0 * INW + i];

        // ================= Phase A: layer-0 recurrence =================
        {
            const float4* wp = (const float4*)(Whh0 + (size_t)r * HH);
            #pragma unroll
            for (int k = 0; k < HH/4; ++k) {
                const float4 v4 = wp[k];
                w[4*k+0]=v4.x; w[4*k+1]=v4.y; w[4*k+2]=v4.z; w[4*k+3]=v4.w;
            }
        }
        __syncthreads();  // xc + carry + (chunk0) zero-init visible

        for (int t = 0; t < tc; ++t) {
            const float4 xv = *(const float4*)(xc + t * INW);   // broadcast
            float a0 = bias0 + xv.x*wx0 + xv.y*wx1 + xv.z*wx2 + xv.w*wx3;
            float a1 = 0.f, a2 = 0.f, a3 = 0.f;
            const float4* hp = (const float4*)(h1c + t * HH);   // h_{t-1}, broadcast
            #pragma unroll
            for (int k = 0; k < HH/4; ++k) {
                const float4 h4 = hp[k];
                a0 += h4.x * w[4*k+0];
                a1 += h4.y * w[4*k+1];
                a2 += h4.z * w[4*k+2];
                a3 += h4.w * w[4*k+3];
            }
            const float acc = (a0 + a1) + (a2 + a3);
            gbuf[r] = ((r >> 7) == 2) ? tanh_(acc) : sigm(acc);
            __syncthreads();
            if (r < HH) {
                const float gi = gbuf[r],        gf = gbuf[HH + r];
                const float gg = gbuf[2*HH + r], go = gbuf[3*HH + r];
                c1 = gf * c1 + gi * gg;
                h1c[(t + 1) * HH + r] = go * tanh_(c1);
            }
            __syncthreads();
        }

        // ================= Phase B: xg1 = h1 @ Wih1^T + biases =========
        {
            const float4* wp = (const float4*)(Wih1 + (size_t)r * HH);
            #pragma unroll
            for (int k = 0; k < HH/4; ++k) {
                const float4 v4 = wp[k];
                w[4*k+0]=v4.x; w[4*k+1]=v4.y; w[4*k+2]=v4.z; w[4*k+3]=v4.w;
            }
        }
        for (int t = 0; t < tc; ++t) {               // no per-t dependency: no barriers
            float a0 = bias1, a1 = 0.f, a2 = 0.f, a3 = 0.f;
            const float4* hp = (const float4*)(h1c + (t + 1) * HH);
            #pragma unroll
            for (int k = 0; k < HH/4; ++k) {
                const float4 h4 = hp[k];
                a0 += h4.x * w[4*k+0];
                a1 += h4.y * w[4*k+1];
                a2 += h4.z * w[4*k+2];
                a3 += h4.w * w[4*k+3];
            }
            xg1c[t * G4 + r] = (a0 + a1) + (a2 + a3);
        }
        __syncthreads();

        // ====== Phase C: layer-1 recurrence + output projection ========
        {
            const float4* wp = (const float4*)(Whh1 + (size_t)r * HH);
            #pragma unroll
            for (int k = 0; k < HH/4; ++k) {
                const float4 v4 = wp[k];
                w[4*k+0]=v4.x; w[4*k+1]=v4.y; w[4*k+2]=v4.z; w[4*k+3]=v4.w;
            }
        }
        for (int t = 0; t < tc; ++t) {
            float a0 = xg1c[t * G4 + r], a1 = 0.f, a2 = 0.f, a3 = 0.f;
            const float4* hp = (const float4*)h2b;   // broadcast
            #pragma unroll
            for (int k = 0; k < HH/4; ++k) {
                const float4 h4 = hp[k];
                a0 += h4.x * w[4*k+0];
                a1 += h4.y * w[4*k+1];
                a2 += h4.z * w[4*k+2];
                a3 += h4.w * w[4*k+3];
            }
            const float acc = (a0 + a1) + (a2 + a3);
            gbuf[r] = ((r >> 7) == 2) ? tanh_(acc) : sigm(acc);
            __syncthreads();
            if (r < HH) {
                const float gi = gbuf[r],        gf = gbuf[HH + r];
                const float gg = gbuf[2*HH + r], go = gbuf[3*HH + r];
                c2 = gf * c2 + gi * gg;
                h2b[r] = go * tanh_(c2);
            }
            __syncthreads();
            // projection v[b,t,:] from the fresh h2 (waves 0..3, one output each)
            if (r < OUTW * 64) {
                const int o = r >> 6, l = r & 63;
                float p = h2b[l] * wl0 + h2b[64 + l] * wl1;
                p += __shfl_xor(p, 32);
                p += __shfl_xor(p, 16);
                p += __shfl_xor(p, 8);
                p += __shfl_xor(p, 4);
                p += __shfl_xor(p, 2);
                p += __shfl_xor(p, 1);
                if (l == 0) vout[(size_t)(t0 + t) * OUTW + o] = p + bl;
            }
        }
        __syncthreads();
    }

    if (r < HH) zout[r] = h2b[r];   // z = zs[:,-1]
}

extern "C" void kernel_launch(void* const* d_in, const int* in_sizes, int n_in,
                              void* d_out, int out_size, void* d_ws, size_t ws_size,
                              hipStream_t stream) {
    const float* x    = (const float*)d_in[0];
    const float* Wih0 = (const float*)d_in[1];
    const float* Whh0 = (const float*)d_in[2];
    const float* bih0 = (const float*)d_in[3];
    const float* bhh0 = (const float*)d_in[4];
    const float* Wih1 = (const float*)d_in[5];
    const float* Whh1 = (const float*)d_in[6];
    const float* bih1 = (const float*)d_in[7];
    const float* bhh1 = (const float*)d_in[8];
    const float* Wlin = (const float*)d_in[9];
    const float* blin = (const float*)d_in[10];
    float* out = (float*)d_out;

    const size_t lds_bytes =
        ((size_t)(TC + 1) * HH + (size_t)TC * G4 + G4 + HH + (size_t)TC * INW) * sizeof(float);

    // allow >64KB dynamic LDS (idempotent host-side call; not a stream op)
    (void)hipFuncSetAttribute((const void*)lstm2_fused,
                              hipFuncAttributeMaxDynamicSharedMemorySize,
                              (int)lds_bytes);

    lstm2_fused<<<dim3(BB), dim3(NT), lds_bytes, stream>>>(
        x, Wih0, Whh0, bih0, bhh0, Wih1, Whh1, bih1, bhh1, Wlin, blin, out);
}

// Round 3
// 30635.727 us; speedup vs baseline: 1.1110x; 1.1110x over previous
//
#include <hip/hip_runtime.h>

#define BB 256
#define TT 2048
#define HH 128
#define G4 512     // 4*H gate rows
#define INW 4
#define OUTW 4
#define TC 56      // time-chunk; LDS-resident
#define NT 1024    // 2 threads per gate row; 64 weights each (fits 128-VGPR budget)
#define HW 64      // half-row width

__device__ __forceinline__ float sigm(float x) {
    return __fdividef(1.f, 1.f + __expf(-x));
}
__device__ __forceinline__ float tanh_(float x) {
    return __fdividef(2.f, 1.f + __expf(-2.f * x)) - 1.f;
}

// R1/R2 lesson: a 128-float per-thread array spills at the 128-VGPR cap no
// matter the waves_per_eu hint (35 GB/dispatch scratch traffic, dur 34ms).
// Fix: 2 threads per row, 64 weights each -> ~104 VGPRs live, no spill.
// 147KB LDS -> 1 block/CU -> 16 waves/CU = 4 waves/EU.
extern "C" __global__ void
__attribute__((amdgpu_flat_work_group_size(NT, NT)))
__attribute__((amdgpu_waves_per_eu(4, 4)))
lstm2_fused(const float* __restrict__ x,
            const float* __restrict__ Wih0, const float* __restrict__ Whh0,
            const float* __restrict__ bih0, const float* __restrict__ bhh0,
            const float* __restrict__ Wih1, const float* __restrict__ Whh1,
            const float* __restrict__ bih1, const float* __restrict__ bhh1,
            const float* __restrict__ Wlin, const float* __restrict__ blin,
            float* __restrict__ out)
{
    extern __shared__ float lds[];
    float* h1c  = lds;                    // (TC+1)*HH : h1 ring; row i = h1 at local step i-1
    float* xg1c = h1c + (TC + 1) * HH;    // TC*G4    : layer-1 input gates for the chunk
    float* gbuf = xg1c + TC * G4;         // G4       : activated gates exchange
    float* h2b  = gbuf + G4;              // HH       : current layer-1 hidden
    float* xc   = h2b + HH;               // TC*INW   : x chunk

    const int i    = threadIdx.x;
    const int row  = i >> 1;              // gate row 0..511
    const int half = i & 1;               // which 64-wide half of the row
    const int hoff = half * HW;
    const int b    = blockIdx.x;

    // half-0 thread of each pair owns bias + x-projection terms
    float bias0 = 0.f, bias1 = 0.f, wx0 = 0.f, wx1 = 0.f, wx2 = 0.f, wx3 = 0.f;
    if (!half) {
        bias0 = bih0[row] + bhh0[row];
        bias1 = bih1[row] + bhh1[row];
        wx0 = Wih0[row*INW+0]; wx1 = Wih0[row*INW+1];
        wx2 = Wih0[row*INW+2]; wx3 = Wih0[row*INW+3];
    }

    // projection params (threads 0..255 = waves 0..3, one output each)
    float wl0 = 0.f, wl1 = 0.f, bl = 0.f;
    if (i < OUTW * 64) {
        const int o = i >> 6, l = i & 63;
        wl0 = Wlin[o*HH + l];
        wl1 = Wlin[o*HH + 64 + l];
        bl  = blin[o];
    }

    float c1 = 0.f, c2 = 0.f;             // cell states (threads i<HH own unit i)
    if (i < HH) { h1c[i] = 0.f; h2b[i] = 0.f; }

    float w[HW];                          // 64-float half-row, static indexing only

    const float* xb   = x   + (size_t)b * TT * INW;
    float*       vout = out + (size_t)b * TT * OUTW;
    float*       zout = out + (size_t)BB * TT * OUTW + (size_t)b * HH;

    for (int t0 = 0; t0 < TT; t0 += TC) {
        const int tc = (TT - t0 < TC) ? (TT - t0) : TC;

        if (t0 > 0 && i < HH) h1c[i] = h1c[TC * HH + i];     // carry h1
        for (int j = i; j < tc * INW; j += NT) xc[j] = xb[t0 * INW + j];

        // ================= Phase A: layer-0 recurrence =================
        {
            const float4* wp = (const float4*)(Whh0 + (size_t)row * HH + hoff);
            #pragma unroll
            for (int k = 0; k < HW/4; ++k) {
                const float4 v4 = wp[k];
                w[4*k+0]=v4.x; w[4*k+1]=v4.y; w[4*k+2]=v4.z; w[4*k+3]=v4.w;
            }
        }
        __syncthreads();

        for (int t = 0; t < tc; ++t) {
            float a0 = 0.f, a1 = 0.f, a2 = 0.f, a3 = 0.f;
            if (!half) {
                const float4 xv = *(const float4*)(xc + t * INW);
                a0 = bias0 + xv.x*wx0 + xv.y*wx1 + xv.z*wx2 + xv.w*wx3;
            }
            const float4* hp = (const float4*)(h1c + t * HH + hoff);
            #pragma unroll
            for (int k = 0; k < HW/4; ++k) {
                const float4 h4 = hp[k];
                a0 += h4.x * w[4*k+0];
                a1 += h4.y * w[4*k+1];
                a2 += h4.z * w[4*k+2];
                a3 += h4.w * w[4*k+3];
            }
            float p = (a0 + a1) + (a2 + a3);
            p += __shfl_xor(p, 1);                           // combine halves
            if (!half) gbuf[row] = ((row >> 7) == 2) ? tanh_(p) : sigm(p);
            __syncthreads();
            if (i < HH) {
                const float gi = gbuf[i],        gf = gbuf[HH + i];
                const float gg = gbuf[2*HH + i], go = gbuf[3*HH + i];
                c1 = gf * c1 + gi * gg;
                h1c[(t + 1) * HH + i] = go * tanh_(c1);
            }
            __syncthreads();
        }

        // ================= Phase B: xg1 = h1 @ Wih1^T + biases =========
        {
            const float4* wp = (const float4*)(Wih1 + (size_t)row * HH + hoff);
            #pragma unroll
            for (int k = 0; k < HW/4; ++k) {
                const float4 v4 = wp[k];
                w[4*k+0]=v4.x; w[4*k+1]=v4.y; w[4*k+2]=v4.z; w[4*k+3]=v4.w;
            }
        }
        for (int t = 0; t < tc; ++t) {                       // no per-t dependency
            float a0 = half ? 0.f : bias1, a1 = 0.f, a2 = 0.f, a3 = 0.f;
            const float4* hp = (const float4*)(h1c + (t + 1) * HH + hoff);
            #pragma unroll
            for (int k = 0; k < HW/4; ++k) {
                const float4 h4 = hp[k];
                a0 += h4.x * w[4*k+0];
                a1 += h4.y * w[4*k+1];
                a2 += h4.z * w[4*k+2];
                a3 += h4.w * w[4*k+3];
            }
            float p = (a0 + a1) + (a2 + a3);
            p += __shfl_xor(p, 1);
            if (!half) xg1c[t * G4 + row] = p;
        }
        __syncthreads();

        // ====== Phase C: layer-1 recurrence + output projection ========
        {
            const float4* wp = (const float4*)(Whh1 + (size_t)row * HH + hoff);
            #pragma unroll
            for (int k = 0; k < HW/4; ++k) {
                const float4 v4 = wp[k];
                w[4*k+0]=v4.x; w[4*k+1]=v4.y; w[4*k+2]=v4.z; w[4*k+3]=v4.w;
            }
        }
        for (int t = 0; t < tc; ++t) {
            float a0 = half ? 0.f : xg1c[t * G4 + row];
            float a1 = 0.f, a2 = 0.f, a3 = 0.f;
            const float4* hp = (const float4*)(h2b + hoff);  // broadcast
            #pragma unroll
            for (int k = 0; k < HW/4; ++k) {
                const float4 h4 = hp[k];
                a0 += h4.x * w[4*k+0];
                a1 += h4.y * w[4*k+1];
                a2 += h4.z * w[4*k+2];
                a3 += h4.w * w[4*k+3];
            }
            float p = (a0 + a1) + (a2 + a3);
            p += __shfl_xor(p, 1);
            if (!half) gbuf[row] = ((row >> 7) == 2) ? tanh_(p) : sigm(p);
            __syncthreads();
            if (i < HH) {
                const float gi = gbuf[i],        gf = gbuf[HH + i];
                const float gg = gbuf[2*HH + i], go = gbuf[3*HH + i];
                c2 = gf * c2 + gi * gg;
                h2b[i] = go * tanh_(c2);
            }
            __syncthreads();
            if (i < OUTW * 64) {                             // v[b,t,:] projection
                const int o = i >> 6, l = i & 63;
                float p2 = h2b[l] * wl0 + h2b[64 + l] * wl1;
                p2 += __shfl_xor(p2, 32);
                p2 += __shfl_xor(p2, 16);
                p2 += __shfl_xor(p2, 8);
                p2 += __shfl_xor(p2, 4);
                p2 += __shfl_xor(p2, 2);
                p2 += __shfl_xor(p2, 1);
                if (l == 0) vout[(size_t)(t0 + t) * OUTW + o] = p2 + bl;
            }
        }
        __syncthreads();
    }

    if (i < HH) zout[i] = h2b[i];   // z = zs[:,-1]
}

extern "C" void kernel_launch(void* const* d_in, const int* in_sizes, int n_in,
                              void* d_out, int out_size, void* d_ws, size_t ws_size,
                              hipStream_t stream) {
    const float* x    = (const float*)d_in[0];
    const float* Wih0 = (const float*)d_in[1];
    const float* Whh0 = (const float*)d_in[2];
    const float* bih0 = (const float*)d_in[3];
    const float* bhh0 = (const float*)d_in[4];
    const float* Wih1 = (const float*)d_in[5];
    const float* Whh1 = (const float*)d_in[6];
    const float* bih1 = (const float*)d_in[7];
    const float* bhh1 = (const float*)d_in[8];
    const float* Wlin = (const float*)d_in[9];
    const float* blin = (const float*)d_in[10];
    float* out = (float*)d_out;

    const size_t lds_bytes =
        ((size_t)(TC + 1) * HH + (size_t)TC * G4 + G4 + HH + (size_t)TC * INW) * sizeof(float);

    (void)hipFuncSetAttribute((const void*)lstm2_fused,
                              hipFuncAttributeMaxDynamicSharedMemorySize,
                              (int)lds_bytes);

    lstm2_fused<<<dim3(BB), dim3(NT), lds_bytes, stream>>>(
        x, Wih0, Whh0, bih0, bhh0, Wih1, Whh1, bih1, bhh1, Wlin, blin, out);
}